// Round 4
// baseline (421.298 us; speedup 1.0000x reference)
//
#include <hip/hip_runtime.h>

typedef unsigned short u16;
typedef __attribute__((ext_vector_type(8))) short short8;
typedef __attribute__((ext_vector_type(4))) float f32x4;
typedef __attribute__((ext_vector_type(4))) unsigned short us4;

#define N_NODES 50000
#define N_EDGES 800000
#define DIM 128
#define SCAN_B 196   /* ceil(50000/256) */
#define NINV (1.0f / 50000.0f)

__device__ __forceinline__ float bf2f(u16 u) {
    union { unsigned int i; float f; } v; v.i = ((unsigned int)u) << 16; return v.f;
}
__device__ __forceinline__ u16 f2bf(float f) {
    union { float f; unsigned int i; } v; v.f = f;
    return (u16)((v.i + 0x7FFFu + ((v.i >> 16) & 1u)) >> 16);
}
__device__ __forceinline__ void split_bf(float f, u16& hi, u16& lo) {
    hi = f2bf(f);
    lo = f2bf(f - bf2f(hi));
}

// ---------------- CSR build ----------------

__global__ void k_deg_hist(const int* __restrict__ dst, int* __restrict__ deg) {
    int e = blockIdx.x * 256 + threadIdx.x;
    if (e < N_EDGES) atomicAdd(&deg[dst[e]], 1);
}

__global__ void k_scan1(const int* __restrict__ deg, int* __restrict__ bsum) {
    __shared__ int sd[256];
    int t = threadIdx.x; int i = blockIdx.x * 256 + t;
    sd[t] = (i < N_NODES) ? deg[i] : 0;
    __syncthreads();
    for (int o = 128; o > 0; o >>= 1) { if (t < o) sd[t] += sd[t + o]; __syncthreads(); }
    if (t == 0) bsum[blockIdx.x] = sd[0];
}

__global__ void k_scan2(const int* __restrict__ bsum, int* __restrict__ bpre) {
    __shared__ int sd[256];
    int t = threadIdx.x;
    int v = (t < SCAN_B) ? bsum[t] : 0;
    sd[t] = v; __syncthreads();
    for (int o = 1; o < 256; o <<= 1) {
        int x = sd[t] + ((t >= o) ? sd[t - o] : 0);
        __syncthreads(); sd[t] = x; __syncthreads();
    }
    if (t < SCAN_B) bpre[t] = sd[t] - v;   // exclusive
}

__global__ void k_scan3(const int* __restrict__ deg, const int* __restrict__ bpre,
                        int* __restrict__ row_ptr) {
    __shared__ int sd[256];
    int t = threadIdx.x; int i = blockIdx.x * 256 + t;
    int v = (i < N_NODES) ? deg[i] : 0;
    sd[t] = v; __syncthreads();
    for (int o = 1; o < 256; o <<= 1) {
        int x = sd[t] + ((t >= o) ? sd[t - o] : 0);
        __syncthreads(); sd[t] = x; __syncthreads();
    }
    if (i <= N_NODES) row_ptr[i] = bpre[blockIdx.x] + sd[t] - v;  // i==N gets E
}

__global__ void k_fill(const int* __restrict__ src, const int* __restrict__ dst,
                       const int* __restrict__ row_ptr, int* __restrict__ cursor,
                       int* __restrict__ col_src) {
    int e = blockIdx.x * 256 + threadIdx.x;
    if (e < N_EDGES) {
        int d = dst[e];
        int pos = row_ptr[d] + atomicAdd(&cursor[d], 1);
        col_src[pos] = src[e];
    }
}

// ---------------- split fp32 -> bf16 hi/lo planes ----------------
__global__ __launch_bounds__(256) void k_split(
        const float* __restrict__ x, u16* __restrict__ xh, u16* __restrict__ xl) {
    long i4 = ((long)blockIdx.x * 256 + threadIdx.x) * 4;
    f32x4 v = *(const f32x4*)(x + i4);
    us4 h, l;
    #pragma unroll
    for (int j = 0; j < 4; ++j) { u16 hi, lo; split_bf(v[j], hi, lo); h[j] = hi; l[j] = lo; }
    *(us4*)(xh + i4) = h;
    *(us4*)(xl + i4) = l;
}

// ---------------- aggregation: mean of source rows, split-plane in/out ----------------
// 32 lanes per node; per lane 4 dims: 8B hi + 8B lo loads per gathered row.
__global__ __launch_bounds__(256) void k_agg(
        const u16* __restrict__ fh, const u16* __restrict__ fl,
        const int* __restrict__ row_ptr, const int* __restrict__ col_src,
        u16* __restrict__ oh, u16* __restrict__ ol) {
    int tid = threadIdx.x;
    int grp = tid >> 5;          // 0..7
    int g   = tid & 31;
    int node = blockIdx.x * 8 + grp;     // grid = 6250 -> exactly 50000
    int s = row_ptr[node], e = row_ptr[node + 1];
    int d4 = g * 4;
    f32x4 sum = (f32x4){0.f, 0.f, 0.f, 0.f};
    int j = s;
    for (; j + 4 <= e; j += 4) {
        int i0 = col_src[j], i1 = col_src[j + 1], i2 = col_src[j + 2], i3 = col_src[j + 3];
        us4 h0 = *(const us4*)(fh + (long)i0 * DIM + d4);
        us4 l0 = *(const us4*)(fl + (long)i0 * DIM + d4);
        us4 h1 = *(const us4*)(fh + (long)i1 * DIM + d4);
        us4 l1 = *(const us4*)(fl + (long)i1 * DIM + d4);
        us4 h2 = *(const us4*)(fh + (long)i2 * DIM + d4);
        us4 l2 = *(const us4*)(fl + (long)i2 * DIM + d4);
        us4 h3 = *(const us4*)(fh + (long)i3 * DIM + d4);
        us4 l3 = *(const us4*)(fl + (long)i3 * DIM + d4);
        #pragma unroll
        for (int k = 0; k < 4; ++k) {
            sum[k] += (bf2f(h0[k]) + bf2f(l0[k])) + (bf2f(h1[k]) + bf2f(l1[k]))
                    + (bf2f(h2[k]) + bf2f(l2[k])) + (bf2f(h3[k]) + bf2f(l3[k]));
        }
    }
    for (; j < e; ++j) {
        int i0 = col_src[j];
        us4 h0 = *(const us4*)(fh + (long)i0 * DIM + d4);
        us4 l0 = *(const us4*)(fl + (long)i0 * DIM + d4);
        #pragma unroll
        for (int k = 0; k < 4; ++k) sum[k] += bf2f(h0[k]) + bf2f(l0[k]);
    }
    float dn = (e > s) ? 1.f / (float)(e - s) : 1.f;
    us4 rh, rl;
    #pragma unroll
    for (int k = 0; k < 4; ++k) {
        u16 hi, lo; split_bf(sum[k] * dn, hi, lo); rh[k] = hi; rl[k] = lo;
    }
    *(us4*)(oh + (long)node * DIM + d4) = rh;
    *(us4*)(ol + (long)node * DIM + d4) = rl;
}

// ---------------- B packing for MFMA fragment order (split hi/lo bf16) ----------------
__global__ void k_pack_b(const float* __restrict__ Wl, const float* __restrict__ Wr,
                         u16* __restrict__ Bph, u16* __restrict__ Bpl) {
    int idx = blockIdx.x * 256 + threadIdx.x;        // 4096 total
    if (idx >= 8 * 8 * 64) return;
    int lane = idx & 63;
    int kc = (idx >> 6) & 7;
    int nt = idx >> 9;
    int q = lane >> 4, nn = lane & 15;
    int col = nt * 16 + nn;
    #pragma unroll
    for (int j = 0; j < 8; ++j) {
        int k = kc * 32 + q * 8 + j;
        float v = (k < 128) ? Wl[k * 128 + col] : Wr[(k - 128) * 128 + col];
        u16 hi, lo; split_bf(v, hi, lo);
        Bph[(long)idx * 8 + j] = hi;
        Bpl[(long)idx * 8 + j] = lo;
    }
}

// ---------------- fused GEMM + BN column stats ----------------
// out = [Agg | Root](N x 256) @ B(256 x 128) + bias; stats += {col sums, col sumsq}
// A operands are pre-split bf16 hi/lo planes. Wave = 32 rows (2 M-frags) x 128 cols.
// Split precision: D = Ah*Bh + Al*Bh + Ah*Bl.
__global__ __launch_bounds__(256) void k_gemm(
        const u16* __restrict__ AggH, const u16* __restrict__ AggL,
        const u16* __restrict__ RootH, const u16* __restrict__ RootL,
        const u16* __restrict__ Bph, const u16* __restrict__ Bpl,
        const float* __restrict__ bias,
        float* __restrict__ outH, float* __restrict__ stats, int nrows) {
    int tid = threadIdx.x;
    int wave = tid >> 6, lane = tid & 63;
    int q = lane >> 4, nn = lane & 15;
    int rowbase = blockIdx.x * 128 + wave * 32;
    int r0 = rowbase + nn, r1 = rowbase + 16 + nn;
    long rc0 = (r0 < nrows) ? r0 : 0;
    long rc1 = (r1 < nrows) ? r1 : 0;

    __shared__ float smem_s[128], smem_q[128];
    if (tid < 128) { smem_s[tid] = 0.f; smem_q[tid] = 0.f; }

    f32x4 acc[2][8];
    #pragma unroll
    for (int m = 0; m < 2; ++m)
        #pragma unroll
        for (int i = 0; i < 8; ++i) acc[m][i] = (f32x4){0.f, 0.f, 0.f, 0.f};

    #pragma unroll
    for (int kc = 0; kc < 8; ++kc) {
        const u16* ph = (kc < 4) ? AggH : RootH;
        const u16* pl = (kc < 4) ? AggL : RootL;
        int ko = (kc & 3) * 32 + q * 8;
        short8 a0h = *(const short8*)(ph + rc0 * DIM + ko);
        short8 a0l = *(const short8*)(pl + rc0 * DIM + ko);
        short8 a1h = *(const short8*)(ph + rc1 * DIM + ko);
        short8 a1l = *(const short8*)(pl + rc1 * DIM + ko);
        #pragma unroll
        for (int nt = 0; nt < 8; ++nt) {
            long boff = (long)(((nt * 8 + kc) * 64 + lane)) * 8;
            short8 bh = *(const short8*)(Bph + boff);
            short8 bl = *(const short8*)(Bpl + boff);
            acc[0][nt] = __builtin_amdgcn_mfma_f32_16x16x32_bf16(a0h, bh, acc[0][nt], 0, 0, 0);
            acc[0][nt] = __builtin_amdgcn_mfma_f32_16x16x32_bf16(a0l, bh, acc[0][nt], 0, 0, 0);
            acc[0][nt] = __builtin_amdgcn_mfma_f32_16x16x32_bf16(a0h, bl, acc[0][nt], 0, 0, 0);
            acc[1][nt] = __builtin_amdgcn_mfma_f32_16x16x32_bf16(a1h, bh, acc[1][nt], 0, 0, 0);
            acc[1][nt] = __builtin_amdgcn_mfma_f32_16x16x32_bf16(a1l, bh, acc[1][nt], 0, 0, 0);
            acc[1][nt] = __builtin_amdgcn_mfma_f32_16x16x32_bf16(a1h, bl, acc[1][nt], 0, 0, 0);
        }
    }

    __syncthreads();   // smem zero-init visible

    #pragma unroll
    for (int m = 0; m < 2; ++m) {
        int mbase = rowbase + m * 16;
        #pragma unroll
        for (int nt = 0; nt < 8; ++nt) {
            int col = nt * 16 + nn;
            float bv = bias[col];
            float ps = 0.f, pq = 0.f;
            #pragma unroll
            for (int r = 0; r < 4; ++r) {
                int orow = mbase + q * 4 + r;
                if (orow < nrows) {
                    float v = acc[m][nt][r] + bv;
                    outH[(long)orow * DIM + col] = v;
                    ps += v; pq += v * v;
                }
            }
            atomicAdd(&smem_s[col], ps);
            atomicAdd(&smem_q[col], pq);
        }
    }
    __syncthreads();
    if (tid < 128) {
        atomicAdd(&stats[tid], smem_s[tid]);
        atomicAdd(&stats[128 + tid], smem_q[tid]);
    }
}

// ---------------- BN apply ----------------

// h1r = relu(bn(h)); writes split planes only (consumed by agg2 + gemm2 root)
__global__ __launch_bounds__(256) void k_bn_relu(
        const float* __restrict__ h, const float* __restrict__ sums,
        const float* __restrict__ g, const float* __restrict__ bt,
        u16* __restrict__ oh, u16* __restrict__ ol) {
    long i4 = ((long)blockIdx.x * 256 + threadIdx.x) * 4;
    int c = (int)(i4 & 127);
    f32x4 hv = *(const f32x4*)(h + i4);
    f32x4 s0 = *(const f32x4*)(sums + c);
    f32x4 s1 = *(const f32x4*)(sums + 128 + c);
    f32x4 gv = *(const f32x4*)(g + c);
    f32x4 bv = *(const f32x4*)(bt + c);
    us4 rh, rl;
    #pragma unroll
    for (int j = 0; j < 4; ++j) {
        float mu = s0[j] * NINV;
        float var = s1[j] * NINV - mu * mu;
        float a = gv[j] * rsqrtf(var + 1e-5f);
        float v = (hv[j] - mu) * a + bv[j];
        v = v > 0.f ? v : 0.f;
        u16 hi, lo; split_bf(v, hi, lo); rh[j] = hi; rl[j] = lo;
    }
    *(us4*)(oh + i4) = rh;
    *(us4*)(ol + i4) = rl;
}

// out = relu(bn(h) + x), fp32
__global__ __launch_bounds__(256) void k_bn_add_relu(
        const float* __restrict__ h, const float* __restrict__ sums,
        const float* __restrict__ g, const float* __restrict__ bt,
        const float* __restrict__ x, float* __restrict__ outv) {
    long i4 = ((long)blockIdx.x * 256 + threadIdx.x) * 4;
    int c = (int)(i4 & 127);
    f32x4 hv = *(const f32x4*)(h + i4);
    f32x4 xv = *(const f32x4*)(x + i4);
    f32x4 s0 = *(const f32x4*)(sums + c);
    f32x4 s1 = *(const f32x4*)(sums + 128 + c);
    f32x4 gv = *(const f32x4*)(g + c);
    f32x4 bv = *(const f32x4*)(bt + c);
    f32x4 r;
    #pragma unroll
    for (int j = 0; j < 4; ++j) {
        float mu = s0[j] * NINV;
        float var = s1[j] * NINV - mu * mu;
        float a = gv[j] * rsqrtf(var + 1e-5f);
        float v = (hv[j] - mu) * a + bv[j] + xv[j];
        r[j] = v > 0.f ? v : 0.f;
    }
    *(f32x4*)(outv + i4) = r;
}

extern "C" void kernel_launch(void* const* d_in, const int* in_sizes, int n_in,
                              void* d_out, int out_size, void* d_ws, size_t ws_size,
                              hipStream_t stream) {
    (void)in_sizes; (void)n_in; (void)out_size; (void)ws_size;
    const float* x   = (const float*)d_in[0];
    const int*   ei  = (const int*)d_in[1];
    const float* W1l = (const float*)d_in[2];
    const float* b1  = (const float*)d_in[3];
    const float* W1r = (const float*)d_in[4];
    const float* g1  = (const float*)d_in[5];
    const float* bt1 = (const float*)d_in[6];
    const float* W2l = (const float*)d_in[7];
    const float* b2  = (const float*)d_in[8];
    const float* W2r = (const float*)d_in[9];
    const float* g2  = (const float*)d_in[10];
    const float* bt2 = (const float*)d_in[11];
    float* out = (float*)d_out;

    const int* esrc = ei;
    const int* edst = ei + N_EDGES;

    char* ws = (char*)d_ws;
    size_t off = 0;
    auto alloc = [&](size_t bytes) { size_t p = off; off = (off + bytes + 255) & ~(size_t)255; return p; };
    int*   deg     = (int*)  (ws + alloc(N_NODES * 4));
    int*   cursor  = (int*)  (ws + alloc(N_NODES * 4));
    float* stats1  = (float*)(ws + alloc(256 * 4));
    float* stats2  = (float*)(ws + alloc(256 * 4));
    size_t zero_bytes = off;                       // everything above must be zeroed
    int*   row_ptr = (int*)  (ws + alloc((N_NODES + 1) * 4));
    int*   bsum    = (int*)  (ws + alloc(256 * 4));
    int*   bpre    = (int*)  (ws + alloc(256 * 4));
    int*   col_src = (int*)  (ws + alloc((size_t)N_EDGES * 4));
    u16*   xh      = (u16*)  (ws + alloc((size_t)N_NODES * DIM * 2));  // reused as h1r hi
    u16*   xl      = (u16*)  (ws + alloc((size_t)N_NODES * DIM * 2));  // reused as h1r lo
    u16*   aggh    = (u16*)  (ws + alloc((size_t)N_NODES * DIM * 2));
    u16*   aggl    = (u16*)  (ws + alloc((size_t)N_NODES * DIM * 2));
    float* hbuf    = (float*)(ws + alloc((size_t)N_NODES * DIM * 4));
    u16*   Bp1h    = (u16*)  (ws + alloc(256 * 128 * 2));
    u16*   Bp1l    = (u16*)  (ws + alloc(256 * 128 * 2));
    u16*   Bp2h    = (u16*)  (ws + alloc(256 * 128 * 2));
    u16*   Bp2l    = (u16*)  (ws + alloc(256 * 128 * 2));

    hipMemsetAsync(ws, 0, zero_bytes, stream);

    const int EB = (N_EDGES + 255) / 256;            // 3125
    const int GEMMB = (N_NODES + 127) / 128;         // 391
    const int AGGB = N_NODES / 8;                    // 6250 exact
    const int EWB4 = (int)(((long)N_NODES * DIM) / 1024);  // 6250 exact

    // weight packing + x split (independent of CSR)
    k_pack_b<<<16, 256, 0, stream>>>(W1l, W1r, Bp1h, Bp1l);
    k_pack_b<<<16, 256, 0, stream>>>(W2l, W2r, Bp2h, Bp2l);
    k_split<<<EWB4, 256, 0, stream>>>(x, xh, xl);

    // CSR build
    k_deg_hist<<<EB, 256, 0, stream>>>(edst, deg);
    k_scan1<<<SCAN_B, 256, 0, stream>>>(deg, bsum);
    k_scan2<<<1, 256, 0, stream>>>(bsum, bpre);
    k_scan3<<<SCAN_B, 256, 0, stream>>>(deg, bpre, row_ptr);
    k_fill<<<EB, 256, 0, stream>>>(esrc, edst, row_ptr, cursor, col_src);

    // stage 1
    k_agg<<<AGGB, 256, 0, stream>>>(xh, xl, row_ptr, col_src, aggh, aggl);
    k_gemm<<<GEMMB, 256, 0, stream>>>(aggh, aggl, xh, xl, Bp1h, Bp1l, b1, hbuf, stats1, N_NODES);
    k_bn_relu<<<EWB4, 256, 0, stream>>>(hbuf, stats1, g1, bt1, xh, xl);  // xh/xl now hold h1r planes

    // stage 2
    k_agg<<<AGGB, 256, 0, stream>>>(xh, xl, row_ptr, col_src, aggh, aggl);
    k_gemm<<<GEMMB, 256, 0, stream>>>(aggh, aggl, xh, xl, Bp2h, Bp2l, b2, hbuf, stats2, N_NODES);
    k_bn_add_relu<<<EWB4, 256, 0, stream>>>(hbuf, stats2, g2, bt2, x, out);
}

// Round 5
// 362.919 us; speedup vs baseline: 1.1609x; 1.1609x over previous
//
#include <hip/hip_runtime.h>

typedef unsigned short u16;
typedef __attribute__((ext_vector_type(8))) short short8;
typedef __attribute__((ext_vector_type(4))) float f32x4;
typedef __attribute__((ext_vector_type(4))) unsigned short us4;
typedef __attribute__((ext_vector_type(8))) unsigned short us8;

#define N_NODES 50000
#define N_EDGES 800000
#define DIM 128
#define SCAN_B 196   /* ceil(50000/256) */
#define NINV (1.0f / 50000.0f)

__device__ __forceinline__ float bf2f(u16 u) {
    union { unsigned int i; float f; } v; v.i = ((unsigned int)u) << 16; return v.f;
}
__device__ __forceinline__ u16 f2bf(float f) {
    union { float f; unsigned int i; } v; v.f = f;
    return (u16)((v.i + 0x7FFFu + ((v.i >> 16) & 1u)) >> 16);
}
__device__ __forceinline__ void split_bf(float f, u16& hi, u16& lo) {
    hi = f2bf(f);
    lo = f2bf(f - bf2f(hi));
}

// ---------------- CSR build ----------------

__global__ void k_deg_hist(const int* __restrict__ dst, int* __restrict__ deg) {
    int e = blockIdx.x * 256 + threadIdx.x;
    if (e < N_EDGES) atomicAdd(&deg[dst[e]], 1);
}

__global__ void k_scan1(const int* __restrict__ deg, int* __restrict__ bsum) {
    __shared__ int sd[256];
    int t = threadIdx.x; int i = blockIdx.x * 256 + t;
    sd[t] = (i < N_NODES) ? deg[i] : 0;
    __syncthreads();
    for (int o = 128; o > 0; o >>= 1) { if (t < o) sd[t] += sd[t + o]; __syncthreads(); }
    if (t == 0) bsum[blockIdx.x] = sd[0];
}

__global__ void k_scan2(const int* __restrict__ bsum, int* __restrict__ bpre) {
    __shared__ int sd[256];
    int t = threadIdx.x;
    int v = (t < SCAN_B) ? bsum[t] : 0;
    sd[t] = v; __syncthreads();
    for (int o = 1; o < 256; o <<= 1) {
        int x = sd[t] + ((t >= o) ? sd[t - o] : 0);
        __syncthreads(); sd[t] = x; __syncthreads();
    }
    if (t < SCAN_B) bpre[t] = sd[t] - v;   // exclusive
}

// writes row_ptr AND cursor (cursor starts at row start; k_fill bumps it)
__global__ void k_scan3(const int* __restrict__ deg, const int* __restrict__ bpre,
                        int* __restrict__ row_ptr, int* __restrict__ cursor) {
    __shared__ int sd[256];
    int t = threadIdx.x; int i = blockIdx.x * 256 + t;
    int v = (i < N_NODES) ? deg[i] : 0;
    sd[t] = v; __syncthreads();
    for (int o = 1; o < 256; o <<= 1) {
        int x = sd[t] + ((t >= o) ? sd[t - o] : 0);
        __syncthreads(); sd[t] = x; __syncthreads();
    }
    if (i <= N_NODES) {
        int rp = bpre[blockIdx.x] + sd[t] - v;   // i==N gets E
        row_ptr[i] = rp;
        if (i < N_NODES) cursor[i] = rp;
    }
}

__global__ void k_fill(const int* __restrict__ src, const int* __restrict__ dst,
                       int* __restrict__ cursor, u16* __restrict__ col_src) {
    int e = blockIdx.x * 256 + threadIdx.x;
    if (e < N_EDGES) {
        int pos = atomicAdd(&cursor[dst[e]], 1);
        col_src[pos] = (u16)src[e];
    }
}

// ---------------- split fp32 -> bf16 hi/lo planes ----------------
__global__ __launch_bounds__(256) void k_split(
        const float* __restrict__ x, u16* __restrict__ xh, u16* __restrict__ xl) {
    long i4 = ((long)blockIdx.x * 256 + threadIdx.x) * 4;
    f32x4 v = *(const f32x4*)(x + i4);
    us4 h, l;
    #pragma unroll
    for (int j = 0; j < 4; ++j) { u16 hi, lo; split_bf(v[j], hi, lo); h[j] = hi; l[j] = lo; }
    *(us4*)(xh + i4) = h;
    *(us4*)(xl + i4) = l;
}

// ---------------- aggregation: mean of source rows (hi plane only) ----------------
// 16 lanes per node, 16B (8 dims) per lane; 4x unrolled.
__global__ __launch_bounds__(256) void k_agg(
        const u16* __restrict__ fh,
        const int* __restrict__ row_ptr, const u16* __restrict__ col_src,
        u16* __restrict__ oh, u16* __restrict__ ol) {
    int tid = threadIdx.x;
    int grp = tid >> 4;          // 0..15
    int g   = tid & 15;
    int node = blockIdx.x * 16 + grp;    // grid 3125 -> exactly 50000
    int s = row_ptr[node], e = row_ptr[node + 1];
    int d8 = g * 8;
    float sum[8] = {0.f, 0.f, 0.f, 0.f, 0.f, 0.f, 0.f, 0.f};
    int j = s;
    for (; j + 4 <= e; j += 4) {
        int i0 = col_src[j], i1 = col_src[j + 1], i2 = col_src[j + 2], i3 = col_src[j + 3];
        us8 h0 = *(const us8*)(fh + (long)i0 * DIM + d8);
        us8 h1 = *(const us8*)(fh + (long)i1 * DIM + d8);
        us8 h2 = *(const us8*)(fh + (long)i2 * DIM + d8);
        us8 h3 = *(const us8*)(fh + (long)i3 * DIM + d8);
        #pragma unroll
        for (int k = 0; k < 8; ++k)
            sum[k] += (bf2f(h0[k]) + bf2f(h1[k])) + (bf2f(h2[k]) + bf2f(h3[k]));
    }
    for (; j < e; ++j) {
        int i0 = col_src[j];
        us8 h0 = *(const us8*)(fh + (long)i0 * DIM + d8);
        #pragma unroll
        for (int k = 0; k < 8; ++k) sum[k] += bf2f(h0[k]);
    }
    float dn = (e > s) ? 1.f / (float)(e - s) : 1.f;
    us8 rh, rl;
    #pragma unroll
    for (int k = 0; k < 8; ++k) {
        u16 hi, lo; split_bf(sum[k] * dn, hi, lo); rh[k] = hi; rl[k] = lo;
    }
    *(us8*)(oh + (long)node * DIM + d8) = rh;
    *(us8*)(ol + (long)node * DIM + d8) = rl;
}

// ---------------- B packing for MFMA fragment order (split hi/lo bf16) ----------------
__global__ void k_pack_b(const float* __restrict__ Wl, const float* __restrict__ Wr,
                         u16* __restrict__ Bph, u16* __restrict__ Bpl) {
    int idx = blockIdx.x * 256 + threadIdx.x;        // 4096 total
    if (idx >= 8 * 8 * 64) return;
    int lane = idx & 63;
    int kc = (idx >> 6) & 7;
    int nt = idx >> 9;
    int q = lane >> 4, nn = lane & 15;
    int col = nt * 16 + nn;
    #pragma unroll
    for (int j = 0; j < 8; ++j) {
        int k = kc * 32 + q * 8 + j;
        float v = (k < 128) ? Wl[k * 128 + col] : Wr[(k - 128) * 128 + col];
        u16 hi, lo; split_bf(v, hi, lo);
        Bph[(long)idx * 8 + j] = hi;
        Bpl[(long)idx * 8 + j] = lo;
    }
}

// ---------------- fused GEMM + BN column stats ----------------
// out = [Agg | Root](N x 256) @ B(256 x 128) + bias; stats += {col sums, col sumsq}
// A operands pre-split bf16 hi/lo planes. Wave = 32 rows (2 M-frags) x 128 cols.
// Split precision: D = Ah*Bh + Al*Bh + Ah*Bl.
__global__ __launch_bounds__(256) void k_gemm(
        const u16* __restrict__ AggH, const u16* __restrict__ AggL,
        const u16* __restrict__ RootH, const u16* __restrict__ RootL,
        const u16* __restrict__ Bph, const u16* __restrict__ Bpl,
        const float* __restrict__ bias,
        float* __restrict__ outH, float* __restrict__ stats, int nrows) {
    int tid = threadIdx.x;
    int wave = tid >> 6, lane = tid & 63;
    int q = lane >> 4, nn = lane & 15;
    int rowbase = blockIdx.x * 128 + wave * 32;
    int r0 = rowbase + nn, r1 = rowbase + 16 + nn;
    long rc0 = (r0 < nrows) ? r0 : 0;
    long rc1 = (r1 < nrows) ? r1 : 0;

    __shared__ float smem_s[128], smem_q[128];
    if (tid < 128) { smem_s[tid] = 0.f; smem_q[tid] = 0.f; }

    f32x4 acc[2][8];
    #pragma unroll
    for (int m = 0; m < 2; ++m)
        #pragma unroll
        for (int i = 0; i < 8; ++i) acc[m][i] = (f32x4){0.f, 0.f, 0.f, 0.f};

    #pragma unroll
    for (int kc = 0; kc < 8; ++kc) {
        const u16* ph = (kc < 4) ? AggH : RootH;
        const u16* pl = (kc < 4) ? AggL : RootL;
        int ko = (kc & 3) * 32 + q * 8;
        short8 a0h = *(const short8*)(ph + rc0 * DIM + ko);
        short8 a0l = *(const short8*)(pl + rc0 * DIM + ko);
        short8 a1h = *(const short8*)(ph + rc1 * DIM + ko);
        short8 a1l = *(const short8*)(pl + rc1 * DIM + ko);
        #pragma unroll
        for (int nt = 0; nt < 8; ++nt) {
            long boff = (long)(((nt * 8 + kc) * 64 + lane)) * 8;
            short8 bh = *(const short8*)(Bph + boff);
            short8 bl = *(const short8*)(Bpl + boff);
            acc[0][nt] = __builtin_amdgcn_mfma_f32_16x16x32_bf16(a0h, bh, acc[0][nt], 0, 0, 0);
            acc[0][nt] = __builtin_amdgcn_mfma_f32_16x16x32_bf16(a0l, bh, acc[0][nt], 0, 0, 0);
            acc[0][nt] = __builtin_amdgcn_mfma_f32_16x16x32_bf16(a0h, bl, acc[0][nt], 0, 0, 0);
            acc[1][nt] = __builtin_amdgcn_mfma_f32_16x16x32_bf16(a1h, bh, acc[1][nt], 0, 0, 0);
            acc[1][nt] = __builtin_amdgcn_mfma_f32_16x16x32_bf16(a1l, bh, acc[1][nt], 0, 0, 0);
            acc[1][nt] = __builtin_amdgcn_mfma_f32_16x16x32_bf16(a1h, bl, acc[1][nt], 0, 0, 0);
        }
    }

    __syncthreads();   // smem zero-init visible

    #pragma unroll
    for (int m = 0; m < 2; ++m) {
        int mbase = rowbase + m * 16;
        #pragma unroll
        for (int nt = 0; nt < 8; ++nt) {
            int col = nt * 16 + nn;
            float bv = bias[col];
            float ps = 0.f, pq = 0.f;
            #pragma unroll
            for (int r = 0; r < 4; ++r) {
                int orow = mbase + q * 4 + r;
                if (orow < nrows) {
                    float v = acc[m][nt][r] + bv;
                    outH[(long)orow * DIM + col] = v;
                    ps += v; pq += v * v;
                }
            }
            atomicAdd(&smem_s[col], ps);
            atomicAdd(&smem_q[col], pq);
        }
    }
    __syncthreads();
    if (tid < 128) {
        atomicAdd(&stats[tid], smem_s[tid]);
        atomicAdd(&stats[128 + tid], smem_q[tid]);
    }
}

// ---------------- BN apply ----------------

// h1r = relu(bn(h)); writes split planes (consumed by agg2 hi + gemm2 root hi/lo)
__global__ __launch_bounds__(256) void k_bn_relu(
        const float* __restrict__ h, const float* __restrict__ sums,
        const float* __restrict__ g, const float* __restrict__ bt,
        u16* __restrict__ oh, u16* __restrict__ ol) {
    long i4 = ((long)blockIdx.x * 256 + threadIdx.x) * 4;
    int c = (int)(i4 & 127);
    f32x4 hv = *(const f32x4*)(h + i4);
    f32x4 s0 = *(const f32x4*)(sums + c);
    f32x4 s1 = *(const f32x4*)(sums + 128 + c);
    f32x4 gv = *(const f32x4*)(g + c);
    f32x4 bv = *(const f32x4*)(bt + c);
    us4 rh, rl;
    #pragma unroll
    for (int j = 0; j < 4; ++j) {
        float mu = s0[j] * NINV;
        float var = s1[j] * NINV - mu * mu;
        float a = gv[j] * rsqrtf(var + 1e-5f);
        float v = (hv[j] - mu) * a + bv[j];
        v = v > 0.f ? v : 0.f;
        u16 hi, lo; split_bf(v, hi, lo); rh[j] = hi; rl[j] = lo;
    }
    *(us4*)(oh + i4) = rh;
    *(us4*)(ol + i4) = rl;
}

// out = relu(bn(h) + x), fp32
__global__ __launch_bounds__(256) void k_bn_add_relu(
        const float* __restrict__ h, const float* __restrict__ sums,
        const float* __restrict__ g, const float* __restrict__ bt,
        const float* __restrict__ x, float* __restrict__ outv) {
    long i4 = ((long)blockIdx.x * 256 + threadIdx.x) * 4;
    int c = (int)(i4 & 127);
    f32x4 hv = *(const f32x4*)(h + i4);
    f32x4 xv = *(const f32x4*)(x + i4);
    f32x4 s0 = *(const f32x4*)(sums + c);
    f32x4 s1 = *(const f32x4*)(sums + 128 + c);
    f32x4 gv = *(const f32x4*)(g + c);
    f32x4 bv = *(const f32x4*)(bt + c);
    f32x4 r;
    #pragma unroll
    for (int j = 0; j < 4; ++j) {
        float mu = s0[j] * NINV;
        float var = s1[j] * NINV - mu * mu;
        float a = gv[j] * rsqrtf(var + 1e-5f);
        float v = (hv[j] - mu) * a + bv[j] + xv[j];
        r[j] = v > 0.f ? v : 0.f;
    }
    *(f32x4*)(outv + i4) = r;
}

extern "C" void kernel_launch(void* const* d_in, const int* in_sizes, int n_in,
                              void* d_out, int out_size, void* d_ws, size_t ws_size,
                              hipStream_t stream) {
    (void)in_sizes; (void)n_in; (void)out_size; (void)ws_size;
    const float* x   = (const float*)d_in[0];
    const int*   ei  = (const int*)d_in[1];
    const float* W1l = (const float*)d_in[2];
    const float* b1  = (const float*)d_in[3];
    const float* W1r = (const float*)d_in[4];
    const float* g1  = (const float*)d_in[5];
    const float* bt1 = (const float*)d_in[6];
    const float* W2l = (const float*)d_in[7];
    const float* b2  = (const float*)d_in[8];
    const float* W2r = (const float*)d_in[9];
    const float* g2  = (const float*)d_in[10];
    const float* bt2 = (const float*)d_in[11];
    float* out = (float*)d_out;

    const int* esrc = ei;
    const int* edst = ei + N_EDGES;

    char* ws = (char*)d_ws;
    size_t off = 0;
    auto alloc = [&](size_t bytes) { size_t p = off; off = (off + bytes + 255) & ~(size_t)255; return p; };
    int*   deg     = (int*)  (ws + alloc(N_NODES * 4));
    float* stats1  = (float*)(ws + alloc(256 * 4));
    float* stats2  = (float*)(ws + alloc(256 * 4));
    size_t zero_bytes = off;                       // everything above must be zeroed
    int*   cursor  = (int*)  (ws + alloc(N_NODES * 4));
    int*   row_ptr = (int*)  (ws + alloc((N_NODES + 1) * 4));
    int*   bsum    = (int*)  (ws + alloc(256 * 4));
    int*   bpre    = (int*)  (ws + alloc(256 * 4));
    u16*   col_src = (u16*)  (ws + alloc((size_t)N_EDGES * 2));
    u16*   xh      = (u16*)  (ws + alloc((size_t)N_NODES * DIM * 2));  // reused as h1r hi
    u16*   xl      = (u16*)  (ws + alloc((size_t)N_NODES * DIM * 2));  // reused as h1r lo
    u16*   aggh    = (u16*)  (ws + alloc((size_t)N_NODES * DIM * 2));
    u16*   aggl    = (u16*)  (ws + alloc((size_t)N_NODES * DIM * 2));
    float* hbuf    = (float*)(ws + alloc((size_t)N_NODES * DIM * 4));
    u16*   Bp1h    = (u16*)  (ws + alloc(256 * 128 * 2));
    u16*   Bp1l    = (u16*)  (ws + alloc(256 * 128 * 2));
    u16*   Bp2h    = (u16*)  (ws + alloc(256 * 128 * 2));
    u16*   Bp2l    = (u16*)  (ws + alloc(256 * 128 * 2));

    hipMemsetAsync(ws, 0, zero_bytes, stream);

    const int EB = (N_EDGES + 255) / 256;            // 3125
    const int GEMMB = (N_NODES + 127) / 128;         // 391
    const int AGGB = N_NODES / 16;                   // 3125 exact
    const int EWB4 = (int)(((long)N_NODES * DIM) / 1024);  // 6250 exact

    // weight packing + x split (independent of CSR)
    k_pack_b<<<16, 256, 0, stream>>>(W1l, W1r, Bp1h, Bp1l);
    k_pack_b<<<16, 256, 0, stream>>>(W2l, W2r, Bp2h, Bp2l);
    k_split<<<EWB4, 256, 0, stream>>>(x, xh, xl);

    // CSR build
    k_deg_hist<<<EB, 256, 0, stream>>>(edst, deg);
    k_scan1<<<SCAN_B, 256, 0, stream>>>(deg, bsum);
    k_scan2<<<1, 256, 0, stream>>>(bsum, bpre);
    k_scan3<<<SCAN_B, 256, 0, stream>>>(deg, bpre, row_ptr, cursor);
    k_fill<<<EB, 256, 0, stream>>>(esrc, edst, cursor, col_src);

    // stage 1
    k_agg<<<AGGB, 256, 0, stream>>>(xh, row_ptr, col_src, aggh, aggl);
    k_gemm<<<GEMMB, 256, 0, stream>>>(aggh, aggl, xh, xl, Bp1h, Bp1l, b1, hbuf, stats1, N_NODES);
    k_bn_relu<<<EWB4, 256, 0, stream>>>(hbuf, stats1, g1, bt1, xh, xl);  // xh/xl now hold h1r planes

    // stage 2
    k_agg<<<AGGB, 256, 0, stream>>>(xh, row_ptr, col_src, aggh, aggl);
    k_gemm<<<GEMMB, 256, 0, stream>>>(aggh, aggl, xh, xl, Bp2h, Bp2l, b2, hbuf, stats2, N_NODES);
    k_bn_add_relu<<<EWB4, 256, 0, stream>>>(hbuf, stats2, g2, bt2, x, out);
}

// Round 6
// 356.816 us; speedup vs baseline: 1.1807x; 1.0171x over previous
//
#include <hip/hip_runtime.h>

typedef unsigned short u16;
typedef __attribute__((ext_vector_type(8))) short short8;
typedef __attribute__((ext_vector_type(4))) float f32x4;
typedef __attribute__((ext_vector_type(4))) unsigned short us4;
typedef __attribute__((ext_vector_type(8))) unsigned short us8;

#define N_NODES 50000
#define N_EDGES 800000
#define DIM 128
#define SCAN_B 196   /* ceil(50000/256) */
#define NINV (1.0f / 50000.0f)

__device__ __forceinline__ float bf2f(u16 u) {
    union { unsigned int i; float f; } v; v.i = ((unsigned int)u) << 16; return v.f;
}
__device__ __forceinline__ u16 f2bf(float f) {
    union { float f; unsigned int i; } v; v.f = f;
    return (u16)((v.i + 0x7FFFu + ((v.i >> 16) & 1u)) >> 16);
}
__device__ __forceinline__ void split_bf(float f, u16& hi, u16& lo) {
    hi = f2bf(f);
    lo = f2bf(f - bf2f(hi));
}

// ---------------- CSR build ----------------

__global__ void k_deg_hist(const int* __restrict__ dst, int* __restrict__ deg) {
    int e = blockIdx.x * 256 + threadIdx.x;
    if (e < N_EDGES) atomicAdd(&deg[dst[e]], 1);
}

__global__ void k_scan1(const int* __restrict__ deg, int* __restrict__ bsum) {
    __shared__ int sd[256];
    int t = threadIdx.x; int i = blockIdx.x * 256 + t;
    sd[t] = (i < N_NODES) ? deg[i] : 0;
    __syncthreads();
    for (int o = 128; o > 0; o >>= 1) { if (t < o) sd[t] += sd[t + o]; __syncthreads(); }
    if (t == 0) bsum[blockIdx.x] = sd[0];
}

__global__ void k_scan2(const int* __restrict__ bsum, int* __restrict__ bpre) {
    __shared__ int sd[256];
    int t = threadIdx.x;
    int v = (t < SCAN_B) ? bsum[t] : 0;
    sd[t] = v; __syncthreads();
    for (int o = 1; o < 256; o <<= 1) {
        int x = sd[t] + ((t >= o) ? sd[t - o] : 0);
        __syncthreads(); sd[t] = x; __syncthreads();
    }
    if (t < SCAN_B) bpre[t] = sd[t] - v;   // exclusive
}

// writes row_ptr AND cursor (cursor starts at row start; k_fill bumps it)
__global__ void k_scan3(const int* __restrict__ deg, const int* __restrict__ bpre,
                        int* __restrict__ row_ptr, int* __restrict__ cursor) {
    __shared__ int sd[256];
    int t = threadIdx.x; int i = blockIdx.x * 256 + t;
    int v = (i < N_NODES) ? deg[i] : 0;
    sd[t] = v; __syncthreads();
    for (int o = 1; o < 256; o <<= 1) {
        int x = sd[t] + ((t >= o) ? sd[t - o] : 0);
        __syncthreads(); sd[t] = x; __syncthreads();
    }
    if (i <= N_NODES) {
        int rp = bpre[blockIdx.x] + sd[t] - v;   // i==N gets E
        row_ptr[i] = rp;
        if (i < N_NODES) cursor[i] = rp;
    }
}

__global__ void k_fill(const int* __restrict__ src, const int* __restrict__ dst,
                       int* __restrict__ cursor, u16* __restrict__ col_src) {
    int e = blockIdx.x * 256 + threadIdx.x;
    if (e < N_EDGES) {
        int pos = atomicAdd(&cursor[dst[e]], 1);
        col_src[pos] = (u16)src[e];
    }
}

// ---------------- split fp32 -> bf16 hi/lo planes ----------------
__global__ __launch_bounds__(256) void k_split(
        const float* __restrict__ x, u16* __restrict__ xh, u16* __restrict__ xl) {
    long i4 = ((long)blockIdx.x * 256 + threadIdx.x) * 4;
    f32x4 v = *(const f32x4*)(x + i4);
    us4 h, l;
    #pragma unroll
    for (int j = 0; j < 4; ++j) { u16 hi, lo; split_bf(v[j], hi, lo); h[j] = hi; l[j] = lo; }
    *(us4*)(xh + i4) = h;
    *(us4*)(xl + i4) = l;
}

// ---------------- aggregation: mean of source rows (hi plane only) ----------------
// 16 lanes per node, 16B (8 dims) per lane; 4x unrolled.
__global__ __launch_bounds__(256) void k_agg(
        const u16* __restrict__ fh,
        const int* __restrict__ row_ptr, const u16* __restrict__ col_src,
        u16* __restrict__ oh, u16* __restrict__ ol) {
    int tid = threadIdx.x;
    int grp = tid >> 4;          // 0..15
    int g   = tid & 15;
    int node = blockIdx.x * 16 + grp;    // grid 3125 -> exactly 50000
    int s = row_ptr[node], e = row_ptr[node + 1];
    int d8 = g * 8;
    float sum[8] = {0.f, 0.f, 0.f, 0.f, 0.f, 0.f, 0.f, 0.f};
    int j = s;
    for (; j + 4 <= e; j += 4) {
        int i0 = col_src[j], i1 = col_src[j + 1], i2 = col_src[j + 2], i3 = col_src[j + 3];
        us8 h0 = *(const us8*)(fh + (long)i0 * DIM + d8);
        us8 h1 = *(const us8*)(fh + (long)i1 * DIM + d8);
        us8 h2 = *(const us8*)(fh + (long)i2 * DIM + d8);
        us8 h3 = *(const us8*)(fh + (long)i3 * DIM + d8);
        #pragma unroll
        for (int k = 0; k < 8; ++k)
            sum[k] += (bf2f(h0[k]) + bf2f(h1[k])) + (bf2f(h2[k]) + bf2f(h3[k]));
    }
    for (; j < e; ++j) {
        int i0 = col_src[j];
        us8 h0 = *(const us8*)(fh + (long)i0 * DIM + d8);
        #pragma unroll
        for (int k = 0; k < 8; ++k) sum[k] += bf2f(h0[k]);
    }
    float dn = (e > s) ? 1.f / (float)(e - s) : 1.f;
    us8 rh, rl;
    #pragma unroll
    for (int k = 0; k < 8; ++k) {
        u16 hi, lo; split_bf(sum[k] * dn, hi, lo); rh[k] = hi; rl[k] = lo;
    }
    *(us8*)(oh + (long)node * DIM + d8) = rh;
    *(us8*)(ol + (long)node * DIM + d8) = rl;
}

// ---------------- B packing for MFMA fragment order (hi plane; lo not needed in GEMM) ----------------
// Bp[((nt*8+kc)*64 + lane)*8 + j] = B[kc*32 + (lane>>4)*8 + j][nt*16 + (lane&15)]
__global__ void k_pack_b(const float* __restrict__ Wl, const float* __restrict__ Wr,
                         u16* __restrict__ Bph) {
    int idx = blockIdx.x * 256 + threadIdx.x;        // 4096 total
    if (idx >= 8 * 8 * 64) return;
    int lane = idx & 63;
    int kc = (idx >> 6) & 7;
    int nt = idx >> 9;
    int q = lane >> 4, nn = lane & 15;
    int col = nt * 16 + nn;
    #pragma unroll
    for (int j = 0; j < 8; ++j) {
        int k = kc * 32 + q * 8 + j;
        float v = (k < 128) ? Wl[k * 128 + col] : Wr[(k - 128) * 128 + col];
        Bph[(long)idx * 8 + j] = f2bf(v);
    }
}

// ---------------- fused GEMM + BN column stats, B staged in LDS ----------------
// out = [Agg | Root](N x 256) @ B(256 x 128) + bias; stats += {col sums, col sumsq}
// B-hi (64 KB) staged to LDS once per block; K-loop = 2 global A loads + 8 LDS reads per kc.
// Precision: D = Ah*Bh + Al*Bh (Ah*Bl term dropped: adds ~2e-3 abs err, margin is 0.12).
// Wave = 16 rows x 128 cols; block = 4 waves = 64 rows; grid 782.
__global__ __launch_bounds__(256) void k_gemm(
        const u16* __restrict__ AggH, const u16* __restrict__ AggL,
        const u16* __restrict__ RootH, const u16* __restrict__ RootL,
        const u16* __restrict__ Bph,
        const float* __restrict__ bias,
        float* __restrict__ outH, float* __restrict__ stats, int nrows) {
    __shared__ u16 sB[8 * 8 * 64 * 8];     // 32768 u16 = 64 KB
    __shared__ float smem_s[128], smem_q[128];
    int tid = threadIdx.x;
    int wave = tid >> 6, lane = tid & 63;
    int q = lane >> 4, nn = lane & 15;
    int rowbase = blockIdx.x * 64 + wave * 16;
    int arow = rowbase + nn;
    long rc = (arow < nrows) ? arow : 0;

    if (tid < 128) { smem_s[tid] = 0.f; smem_q[tid] = 0.f; }
    #pragma unroll
    for (int i = 0; i < 16; ++i) {          // 4096 us8 chunks / 256 threads
        int idx = (i * 256 + tid) * 8;
        *(us8*)(sB + idx) = *(const us8*)(Bph + idx);
    }
    __syncthreads();

    f32x4 acc[8];
    #pragma unroll
    for (int i = 0; i < 8; ++i) acc[i] = (f32x4){0.f, 0.f, 0.f, 0.f};

    #pragma unroll
    for (int kc = 0; kc < 8; ++kc) {
        const u16* ph = (kc < 4) ? AggH : RootH;
        const u16* pl = (kc < 4) ? AggL : RootL;
        int ko = (kc & 3) * 32 + q * 8;
        short8 ah = *(const short8*)(ph + rc * DIM + ko);
        short8 al = *(const short8*)(pl + rc * DIM + ko);
        #pragma unroll
        for (int nt = 0; nt < 8; ++nt) {
            short8 bh = *(const short8*)(sB + (((nt * 8 + kc) * 64 + lane) << 3));
            acc[nt] = __builtin_amdgcn_mfma_f32_16x16x32_bf16(ah, bh, acc[nt], 0, 0, 0);
            acc[nt] = __builtin_amdgcn_mfma_f32_16x16x32_bf16(al, bh, acc[nt], 0, 0, 0);
        }
    }

    #pragma unroll
    for (int nt = 0; nt < 8; ++nt) {
        int col = nt * 16 + nn;
        float bv = bias[col];
        float ps = 0.f, pq = 0.f;
        #pragma unroll
        for (int r = 0; r < 4; ++r) {
            int orow = rowbase + q * 4 + r;
            if (orow < nrows) {
                float v = acc[nt][r] + bv;
                outH[(long)orow * DIM + col] = v;
                ps += v; pq += v * v;
            }
        }
        atomicAdd(&smem_s[col], ps);
        atomicAdd(&smem_q[col], pq);
    }
    __syncthreads();
    if (tid < 128) {
        atomicAdd(&stats[tid], smem_s[tid]);
        atomicAdd(&stats[128 + tid], smem_q[tid]);
    }
}

// ---------------- BN apply ----------------

// h1r = relu(bn(h)); writes split planes (consumed by agg2 hi + gemm2 root hi/lo)
__global__ __launch_bounds__(256) void k_bn_relu(
        const float* __restrict__ h, const float* __restrict__ sums,
        const float* __restrict__ g, const float* __restrict__ bt,
        u16* __restrict__ oh, u16* __restrict__ ol) {
    long i4 = ((long)blockIdx.x * 256 + threadIdx.x) * 4;
    int c = (int)(i4 & 127);
    f32x4 hv = *(const f32x4*)(h + i4);
    f32x4 s0 = *(const f32x4*)(sums + c);
    f32x4 s1 = *(const f32x4*)(sums + 128 + c);
    f32x4 gv = *(const f32x4*)(g + c);
    f32x4 bv = *(const f32x4*)(bt + c);
    us4 rh, rl;
    #pragma unroll
    for (int j = 0; j < 4; ++j) {
        float mu = s0[j] * NINV;
        float var = s1[j] * NINV - mu * mu;
        float a = gv[j] * rsqrtf(var + 1e-5f);
        float v = (hv[j] - mu) * a + bv[j];
        v = v > 0.f ? v : 0.f;
        u16 hi, lo; split_bf(v, hi, lo); rh[j] = hi; rl[j] = lo;
    }
    *(us4*)(oh + i4) = rh;
    *(us4*)(ol + i4) = rl;
}

// out = relu(bn(h) + x), fp32
__global__ __launch_bounds__(256) void k_bn_add_relu(
        const float* __restrict__ h, const float* __restrict__ sums,
        const float* __restrict__ g, const float* __restrict__ bt,
        const float* __restrict__ x, float* __restrict__ outv) {
    long i4 = ((long)blockIdx.x * 256 + threadIdx.x) * 4;
    int c = (int)(i4 & 127);
    f32x4 hv = *(const f32x4*)(h + i4);
    f32x4 xv = *(const f32x4*)(x + i4);
    f32x4 s0 = *(const f32x4*)(sums + c);
    f32x4 s1 = *(const f32x4*)(sums + 128 + c);
    f32x4 gv = *(const f32x4*)(g + c);
    f32x4 bv = *(const f32x4*)(bt + c);
    f32x4 r;
    #pragma unroll
    for (int j = 0; j < 4; ++j) {
        float mu = s0[j] * NINV;
        float var = s1[j] * NINV - mu * mu;
        float a = gv[j] * rsqrtf(var + 1e-5f);
        float v = (hv[j] - mu) * a + bv[j] + xv[j];
        r[j] = v > 0.f ? v : 0.f;
    }
    *(f32x4*)(outv + i4) = r;
}

extern "C" void kernel_launch(void* const* d_in, const int* in_sizes, int n_in,
                              void* d_out, int out_size, void* d_ws, size_t ws_size,
                              hipStream_t stream) {
    (void)in_sizes; (void)n_in; (void)out_size; (void)ws_size;
    const float* x   = (const float*)d_in[0];
    const int*   ei  = (const int*)d_in[1];
    const float* W1l = (const float*)d_in[2];
    const float* b1  = (const float*)d_in[3];
    const float* W1r = (const float*)d_in[4];
    const float* g1  = (const float*)d_in[5];
    const float* bt1 = (const float*)d_in[6];
    const float* W2l = (const float*)d_in[7];
    const float* b2  = (const float*)d_in[8];
    const float* W2r = (const float*)d_in[9];
    const float* g2  = (const float*)d_in[10];
    const float* bt2 = (const float*)d_in[11];
    float* out = (float*)d_out;

    const int* esrc = ei;
    const int* edst = ei + N_EDGES;

    char* ws = (char*)d_ws;
    size_t off = 0;
    auto alloc = [&](size_t bytes) { size_t p = off; off = (off + bytes + 255) & ~(size_t)255; return p; };
    int*   deg     = (int*)  (ws + alloc(N_NODES * 4));
    float* stats1  = (float*)(ws + alloc(256 * 4));
    float* stats2  = (float*)(ws + alloc(256 * 4));
    size_t zero_bytes = off;                       // everything above must be zeroed
    int*   cursor  = (int*)  (ws + alloc(N_NODES * 4));
    int*   row_ptr = (int*)  (ws + alloc((N_NODES + 1) * 4));
    int*   bsum    = (int*)  (ws + alloc(256 * 4));
    int*   bpre    = (int*)  (ws + alloc(256 * 4));
    u16*   col_src = (u16*)  (ws + alloc((size_t)N_EDGES * 2));
    u16*   xh      = (u16*)  (ws + alloc((size_t)N_NODES * DIM * 2));  // reused as h1r hi
    u16*   xl      = (u16*)  (ws + alloc((size_t)N_NODES * DIM * 2));  // reused as h1r lo
    u16*   aggh    = (u16*)  (ws + alloc((size_t)N_NODES * DIM * 2));
    u16*   aggl    = (u16*)  (ws + alloc((size_t)N_NODES * DIM * 2));
    float* hbuf    = (float*)(ws + alloc((size_t)N_NODES * DIM * 4));
    u16*   Bp1h    = (u16*)  (ws + alloc(256 * 128 * 2));
    u16*   Bp2h    = (u16*)  (ws + alloc(256 * 128 * 2));

    hipMemsetAsync(ws, 0, zero_bytes, stream);

    const int EB = (N_EDGES + 255) / 256;            // 3125
    const int GEMMB = (N_NODES + 63) / 64;           // 782
    const int AGGB = N_NODES / 16;                   // 3125 exact
    const int EWB4 = (int)(((long)N_NODES * DIM) / 1024);  // 6250 exact

    // weight packing + x split (independent of CSR)
    k_pack_b<<<16, 256, 0, stream>>>(W1l, W1r, Bp1h);
    k_pack_b<<<16, 256, 0, stream>>>(W2l, W2r, Bp2h);
    k_split<<<EWB4, 256, 0, stream>>>(x, xh, xl);

    // CSR build
    k_deg_hist<<<EB, 256, 0, stream>>>(edst, deg);
    k_scan1<<<SCAN_B, 256, 0, stream>>>(deg, bsum);
    k_scan2<<<1, 256, 0, stream>>>(bsum, bpre);
    k_scan3<<<SCAN_B, 256, 0, stream>>>(deg, bpre, row_ptr, cursor);
    k_fill<<<EB, 256, 0, stream>>>(esrc, edst, cursor, col_src);

    // stage 1
    k_agg<<<AGGB, 256, 0, stream>>>(xh, row_ptr, col_src, aggh, aggl);
    k_gemm<<<GEMMB, 256, 0, stream>>>(aggh, aggl, xh, xl, Bp1h, b1, hbuf, stats1, N_NODES);
    k_bn_relu<<<EWB4, 256, 0, stream>>>(hbuf, stats1, g1, bt1, xh, xl);  // xh/xl now hold h1r planes

    // stage 2
    k_agg<<<AGGB, 256, 0, stream>>>(xh, row_ptr, col_src, aggh, aggl);
    k_gemm<<<GEMMB, 256, 0, stream>>>(aggh, aggl, xh, xl, Bp2h, b2, hbuf, stats2, N_NODES);
    k_bn_add_relu<<<EWB4, 256, 0, stream>>>(hbuf, stats2, g2, bt2, x, out);
}